// Round 3
// baseline (193.296 us; speedup 1.0000x reference)
//
#include <hip/hip_runtime.h>
#include <hip/hip_bf16.h>

// out[M=131072, N=512] = x[M, K=512] @ W^T[N=512, K=512] + bias[N]
// fp32 in/out; bf16 MFMA (fp32 accum).
//
// Kernel 1: repack W fp32 -> bf16 MFMA-fragment layout in d_ws (512 KB).
// Kernel 2: GEMM. BM=128 x BN=512 (x read once from HBM), BK=32, 16 K-steps.
//   1024 threads = 16 waves (2x8), wave tile 64x64. A double-buffered in LDS
//   (2x8 KB, XOR-swizzled, measured conflict-free). B-fragments straight from
//   repacked global (L2-resident).
//   Round-3 changes: raw s_barrier + lgkmcnt-only wait (NO vmcnt drain --
//   prefetch stays in flight across barriers, T4), 3-deep x prefetch,
//   B-loads issued pre-barrier so L2 latency hides under the barrier wait,
//   nontemporal C stores, launch_bounds regs<=128 for 4 waves/SIMD.

#define M_TOTAL 131072
#define KDIM 512
#define NDIM 512
#define BM 128
#define BK 32
#define NKSTEP 16

typedef __attribute__((ext_vector_type(8))) short bf16x8;
typedef __attribute__((ext_vector_type(4))) float f32x4;
typedef __attribute__((ext_vector_type(4))) float fv4;
typedef __attribute__((ext_vector_type(4))) int iv4;
typedef __attribute__((ext_vector_type(2))) int iv2;

__device__ __forceinline__ unsigned short f2bf(float f) {
    union { float f; unsigned u; } c; c.f = f;
    unsigned r = c.u + 0x7fffu + ((c.u >> 16) & 1u);  // RNE
    return (unsigned short)(r >> 16);
}

// wf[((t*16+kb)*64 + l)*8 + j] = bf16( W[t*16 + (l&15)][kb*32 + (l>>4)*8 + j] )
__global__ void repack_w_kernel(const float* __restrict__ w,
                                unsigned short* __restrict__ wf) {
    const int gtid = blockIdx.x * 256 + threadIdx.x;  // 0..32767
    const int tk = gtid >> 6;   // t*16 + kb
    const int l  = gtid & 63;
    const int n  = (tk >> 4) * 16 + (l & 15);
    const int k0 = (tk & 15) * 32 + (l >> 4) * 8;
    const fv4* src = reinterpret_cast<const fv4*>(w + n * KDIM + k0);
    fv4 lo = src[0], hi = src[1];
    union { unsigned short us[8]; iv4 v; } p;
#pragma unroll
    for (int i = 0; i < 4; ++i) { p.us[i] = f2bf(lo[i]); p.us[4 + i] = f2bf(hi[i]); }
    *reinterpret_cast<iv4*>(wf + tk * 512 + l * 8) = p.v;
}

__global__ __launch_bounds__(1024, 4) void linear_bf16_kernel(
    const float* __restrict__ x, const unsigned short* __restrict__ wf,
    const float* __restrict__ bias, float* __restrict__ out) {
    __shared__ __attribute__((aligned(16))) unsigned short lds_a[2][BM * BK];  // 2 x 8 KB

    const int tid  = threadIdx.x;
    const int lane = tid & 63;
    const int wid  = tid >> 6;   // 0..15
    const int wrow = wid >> 3;   // 0..1
    const int wcol = wid & 7;    // 0..7
    const int fr   = lane & 15;
    const int fc   = lane >> 4;  // k-chunk 0..3

    const int rowbase = blockIdx.x * BM;

    // ---- A staging: thread t -> row t>>3, 4-float quarter t&7 ----
    const int srow = tid >> 3;   // 0..127
    const int sq   = tid & 7;    // 0..7
    const float* xptr = x + (rowbase + srow) * KDIM + sq * 4;
    const int st_a = srow * BK + (((sq >> 1) ^ ((srow >> 1) & 3)) << 3) + (sq & 1) * 4;

    // ---- A fragment read offset; +m*16 rows keeps swizzle invariant ----
    const int arow0 = wrow * 64 + fr;
    const int aoff  = arow0 * BK + ((fc ^ ((arow0 >> 1) & 3)) << 3);

    // ---- B fragment base: per-lane ptr into repacked W ----
    const unsigned short* wfbase = wf + (wcol * 4 * 16) * 512 + lane * 8;

    f32x4 acc[4][4];
#pragma unroll
    for (int m = 0; m < 4; ++m)
#pragma unroll
        for (int n = 0; n < 4; ++n)
            acc[m][n] = (f32x4){0.f, 0.f, 0.f, 0.f};

    fv4 ra[3];
    bf16x8 bfrag[4];

    auto LOADA = [&](int slot, int kb) {
        ra[slot] = *reinterpret_cast<const fv4*>(xptr + kb * BK);
    };
    auto WRITEA = [&](int buf, int slot) {
        union { unsigned short us[4]; iv2 v; } p;
#pragma unroll
        for (int i = 0; i < 4; ++i) p.us[i] = f2bf(ra[slot][i]);
        *reinterpret_cast<iv2*>(&lds_a[buf][st_a]) = p.v;
    };
    auto LOADB = [&](int kb) {
#pragma unroll
        for (int n = 0; n < 4; ++n)
            bfrag[n] = *reinterpret_cast<const bf16x8*>(wfbase + (n * 16 + kb) * 512);
    };
    auto COMPUTE = [&](int buf) {
        bf16x8 af[4];
#pragma unroll
        for (int m = 0; m < 4; ++m)
            af[m] = *reinterpret_cast<const bf16x8*>(&lds_a[buf][aoff + m * 512]);
#pragma unroll
        for (int n = 0; n < 4; ++n)
#pragma unroll
            for (int m = 0; m < 4; ++m)
                acc[m][n] = __builtin_amdgcn_mfma_f32_16x16x32_bf16(
                    af[m], bfrag[n], acc[m][n], 0, 0, 0);
    };

    // ---- prologue: B(0) + 3-deep A prefetch; write step-0 A ----
    LOADB(0);
    LOADA(0, 0);
    LOADA(1, 1);
    LOADA(2, 2);
    WRITEA(0, 0);  // compiler emits counted vmcnt (2 A-loads stay in flight)
    asm volatile("s_waitcnt lgkmcnt(0)" ::: "memory");
    __builtin_amdgcn_s_barrier();

#pragma unroll
    for (int kb = 0; kb < NKSTEP; ++kb) {
        const int cur = kb & 1;
        if (kb + 3 < NKSTEP) LOADA(kb % 3, kb + 3);       // HBM issue, 3 ahead
        if (kb + 1 < NKSTEP) WRITEA(cur ^ 1, (kb + 1) % 3);
        COMPUTE(cur);                                      // uses B loaded last step
        if (kb + 1 < NKSTEP) LOADB(kb + 1);                // L2 latency hides under barrier
        if (kb + 1 < NKSTEP) {
            asm volatile("s_waitcnt lgkmcnt(0)" ::: "memory");
            __builtin_amdgcn_s_barrier();
        }
    }

    // ---- epilogue: bias + nontemporal stores ----
    float bv[4];
#pragma unroll
    for (int n = 0; n < 4; ++n)
        bv[n] = bias[wcol * 64 + n * 16 + fr];

    float* obase = out + (rowbase + wrow * 64 + fc * 4) * NDIM + wcol * 64 + fr;
#pragma unroll
    for (int m = 0; m < 4; ++m)
#pragma unroll
        for (int j = 0; j < 4; ++j) {
            float* orow = obase + (m * 16 + j) * NDIM;
#pragma unroll
            for (int n = 0; n < 4; ++n)
                __builtin_nontemporal_store(acc[m][n][j] + bv[n], &orow[n * 16]);
        }
}

extern "C" void kernel_launch(void* const* d_in, const int* in_sizes, int n_in,
                              void* d_out, int out_size, void* d_ws, size_t ws_size,
                              hipStream_t stream) {
    const float* x    = (const float*)d_in[0];
    const float* w    = (const float*)d_in[1];
    const float* bias = (const float*)d_in[2];
    float* out        = (float*)d_out;
    unsigned short* wf = (unsigned short*)d_ws;  // 512 KB

    hipLaunchKernelGGL(repack_w_kernel, dim3(128), dim3(256), 0, stream, w, wf);
    hipLaunchKernelGGL(linear_bf16_kernel, dim3(M_TOTAL / BM), dim3(1024), 0, stream,
                       x, wf, bias, out);
}

// Round 4
// 170.624 us; speedup vs baseline: 1.1329x; 1.1329x over previous
//
#include <hip/hip_runtime.h>
#include <hip/hip_bf16.h>

// out[M=131072, N=512] = x[M, K=512] @ W^T[N=512, K=512] + bias[N]
// fp32 in/out; bf16 MFMA (fp32 accum).
//
// Kernel 1: repack W fp32 -> bf16 MFMA-fragment layout in d_ws (512 KB).
// Kernel 2: GEMM. Round-4 geometry: BM=64 x BN=512 (x still read once),
//   512 threads = 8 waves (1x8), wave tile 64x64 (acc=64 AGPR, 64 VGPR ->
//   128 regs/wave -> TWO co-resident blocks/CU; round 2/3 had one 16-wave
//   block/CU in lockstep and ~80% barrier-idle per step). Body is the
//   verified round-2 code: __syncthreads barriers, 2-deep x prefetch,
//   B-fragments direct from repacked global (L2-resident), XOR-swizzled
//   LDS A (measured 0 bank conflicts), plain stores.

#define M_TOTAL 131072
#define KDIM 512
#define NDIM 512
#define BM 64
#define BK 32
#define NKSTEP 16

typedef __attribute__((ext_vector_type(8))) short bf16x8;
typedef __attribute__((ext_vector_type(4))) float f32x4;
typedef __attribute__((ext_vector_type(4))) float fv4;
typedef __attribute__((ext_vector_type(4))) int iv4;
typedef __attribute__((ext_vector_type(2))) int iv2;

__device__ __forceinline__ unsigned short f2bf(float f) {
    union { float f; unsigned u; } c; c.f = f;
    unsigned r = c.u + 0x7fffu + ((c.u >> 16) & 1u);  // RNE
    return (unsigned short)(r >> 16);
}

// wf[((t*16+kb)*64 + l)*8 + j] = bf16( W[t*16 + (l&15)][kb*32 + (l>>4)*8 + j] )
__global__ void repack_w_kernel(const float* __restrict__ w,
                                unsigned short* __restrict__ wf) {
    const int gtid = blockIdx.x * 256 + threadIdx.x;  // 0..32767
    const int tk = gtid >> 6;   // t*16 + kb
    const int l  = gtid & 63;
    const int n  = (tk >> 4) * 16 + (l & 15);
    const int k0 = (tk & 15) * 32 + (l >> 4) * 8;
    const fv4* src = reinterpret_cast<const fv4*>(w + n * KDIM + k0);
    fv4 lo = src[0], hi = src[1];
    union { unsigned short us[8]; iv4 v; } p;
#pragma unroll
    for (int i = 0; i < 4; ++i) { p.us[i] = f2bf(lo[i]); p.us[4 + i] = f2bf(hi[i]); }
    *reinterpret_cast<iv4*>(wf + tk * 512 + l * 8) = p.v;
}

__global__ __launch_bounds__(512, 4) void linear_bf16_kernel(
    const float* __restrict__ x, const unsigned short* __restrict__ wf,
    const float* __restrict__ bias, float* __restrict__ out) {
    __shared__ __attribute__((aligned(16))) unsigned short lds_a[2][BM * BK];  // 2 x 4 KB

    const int tid  = threadIdx.x;
    const int lane = tid & 63;
    const int wcol = tid >> 6;   // 0..7 -> 64-col block
    const int fr   = lane & 15;
    const int fc   = lane >> 4;  // k-chunk 0..3

    const int rowbase = blockIdx.x * BM;

    // ---- A staging: thread t -> row t>>3 (0..63), 4-float quarter t&7 ----
    const int srow = tid >> 3;
    const int sq   = tid & 7;
    const float* xptr = x + (rowbase + srow) * KDIM + sq * 4;
    // physical chunk swizzle (16B granule): c' = c ^ ((row>>1)&3)
    const int st_a = srow * BK + (((sq >> 1) ^ ((srow >> 1) & 3)) << 3) + (sq & 1) * 4;

    // ---- A fragment read offset; +m*16 rows keeps swizzle invariant ----
    const int aoff = fr * BK + ((fc ^ ((fr >> 1) & 3)) << 3);

    // ---- B fragment base: per-lane ptr into repacked W ----
    const unsigned short* wfrag = wf + lane * 8;

    f32x4 acc[4][4];
#pragma unroll
    for (int m = 0; m < 4; ++m)
#pragma unroll
        for (int n = 0; n < 4; ++n)
            acc[m][n] = (f32x4){0.f, 0.f, 0.f, 0.f};

    fv4 ra0, ra1;
    auto LOADA = [&](fv4& r, int kb) {
        r = *reinterpret_cast<const fv4*>(xptr + kb * BK);
    };
    auto WRITEA = [&](int buf, const fv4& r) {
        union { unsigned short us[4]; iv2 v; } p;
#pragma unroll
        for (int i = 0; i < 4; ++i) p.us[i] = f2bf(r[i]);
        *reinterpret_cast<iv2*>(&lds_a[buf][st_a]) = p.v;
    };
    auto COMPUTE = [&](int buf, int kb) {
        bf16x8 bfv[4];
#pragma unroll
        for (int n = 0; n < 4; ++n)
            bfv[n] = *reinterpret_cast<const bf16x8*>(
                wfrag + ((wcol * 4 + n) * 16 + kb) * 512);
        bf16x8 af[4];
#pragma unroll
        for (int m = 0; m < 4; ++m)
            af[m] = *reinterpret_cast<const bf16x8*>(&lds_a[buf][aoff + m * 512]);
#pragma unroll
        for (int n = 0; n < 4; ++n)
#pragma unroll
            for (int m = 0; m < 4; ++m)
                acc[m][n] = __builtin_amdgcn_mfma_f32_16x16x32_bf16(
                    af[m], bfv[n], acc[m][n], 0, 0, 0);
    };

    LOADA(ra0, 0);
    LOADA(ra1, 1);
    WRITEA(0, ra0);
    __syncthreads();

    for (int kb = 0; kb < NKSTEP; kb += 2) {
        COMPUTE(0, kb);
        if (kb + 2 < NKSTEP) LOADA(ra0, kb + 2);
        WRITEA(1, ra1);
        __syncthreads();
        COMPUTE(1, kb + 1);
        if (kb + 3 < NKSTEP) LOADA(ra1, kb + 3);
        if (kb + 2 < NKSTEP) WRITEA(0, ra0);
        __syncthreads();
    }

    // ---- epilogue: bias + store ----
    float bv[4];
#pragma unroll
    for (int n = 0; n < 4; ++n)
        bv[n] = bias[wcol * 64 + n * 16 + fr];

    float* obase = out + (rowbase + fc * 4) * NDIM + wcol * 64 + fr;
#pragma unroll
    for (int m = 0; m < 4; ++m)
#pragma unroll
        for (int j = 0; j < 4; ++j) {
            float* orow = obase + (m * 16 + j) * NDIM;
#pragma unroll
            for (int n = 0; n < 4; ++n)
                orow[n * 16] = acc[m][n][j] + bv[n];
        }
}

extern "C" void kernel_launch(void* const* d_in, const int* in_sizes, int n_in,
                              void* d_out, int out_size, void* d_ws, size_t ws_size,
                              hipStream_t stream) {
    const float* x    = (const float*)d_in[0];
    const float* w    = (const float*)d_in[1];
    const float* bias = (const float*)d_in[2];
    float* out        = (float*)d_out;
    unsigned short* wf = (unsigned short*)d_ws;  // 512 KB

    hipLaunchKernelGGL(repack_w_kernel, dim3(128), dim3(256), 0, stream, w, wf);
    hipLaunchKernelGGL(linear_bf16_kernel, dim3(M_TOTAL / BM), dim3(512), 0, stream,
                       x, wf, bias, out);
}

// Round 5
// 155.042 us; speedup vs baseline: 1.2467x; 1.1005x over previous
//
#include <hip/hip_runtime.h>
#include <hip/hip_bf16.h>

// out[M=131072, N=512] = x[M, K=512] @ W^T[N=512, K=512] + bias[N]
// fp32 in/out; bf16 MFMA (fp32 accum).
//
// Kernel 1: repack W fp32 -> bf16 MFMA-fragment layout in d_ws (512 KB).
// Kernel 2: GEMM, BARRIER-FREE K-loop. BM=64 x BN=512 (x read once from HBM).
//   512 threads = 8 waves, each wave owns a 64x64 tile (acc=64 regs).
//   Prologue: stage the ENTIRE 64x512 A-tile to LDS as bf16 (64 KB),
//   fully-coalesced fp32 loads + one conversion pass, 16B-chunk XOR swizzle
//   (slot = chunk ^ (row&7)) -> bank-floor reads AND writes. ONE barrier.
//   K-loop: 16 unrolled steps, NO barriers -- ds_read_b128 A-frags + B-frags
//   from L2-resident wf + 16 MFMA; compiler pipelines freely, waves drift.
//   2 blocks/CU (2x64KB LDS, regs<=128 via launch_bounds(512,4)).

#define M_TOTAL 131072
#define KDIM 512
#define NDIM 512
#define BM 64
#define NKSTEP 16

typedef __attribute__((ext_vector_type(8))) short bf16x8;
typedef __attribute__((ext_vector_type(4))) float f32x4;
typedef __attribute__((ext_vector_type(4))) float fv4;
typedef __attribute__((ext_vector_type(4))) int iv4;

__device__ __forceinline__ unsigned short f2bf(float f) {
    union { float f; unsigned u; } c; c.f = f;
    unsigned r = c.u + 0x7fffu + ((c.u >> 16) & 1u);  // RNE
    return (unsigned short)(r >> 16);
}

__device__ __forceinline__ iv4 pack8(fv4 lo, fv4 hi) {
    union { unsigned short us[8]; iv4 v; } p;
#pragma unroll
    for (int i = 0; i < 4; ++i) { p.us[i] = f2bf(lo[i]); p.us[4 + i] = f2bf(hi[i]); }
    return p.v;
}

// wf[((t*16+kb)*64 + l)*8 + j] = bf16( W[t*16 + (l&15)][kb*32 + (l>>4)*8 + j] )
__global__ void repack_w_kernel(const float* __restrict__ w,
                                unsigned short* __restrict__ wf) {
    const int gtid = blockIdx.x * 256 + threadIdx.x;  // 0..32767
    const int tk = gtid >> 6;   // t*16 + kb
    const int l  = gtid & 63;
    const int n  = (tk >> 4) * 16 + (l & 15);
    const int k0 = (tk & 15) * 32 + (l >> 4) * 8;
    const fv4* src = reinterpret_cast<const fv4*>(w + n * KDIM + k0);
    *reinterpret_cast<iv4*>(wf + tk * 512 + l * 8) = pack8(src[0], src[1]);
}

__global__ __launch_bounds__(512, 4) void linear_bf16_kernel(
    const float* __restrict__ x, const unsigned short* __restrict__ wf,
    const float* __restrict__ bias, float* __restrict__ out) {
    // 64 rows x 512 cols bf16, 16B-chunk swizzled: ushort idx =
    //   row*512 + ((chunk ^ (row&7))<<3) + (col&7),  chunk = col>>3 (0..63)
    __shared__ __attribute__((aligned(16))) unsigned short lds_a[BM * KDIM];  // 64 KB

    const int tid  = threadIdx.x;
    const int lane = tid & 63;
    const int wcol = tid >> 6;   // 0..7 -> 64-col block
    const int fr   = lane & 15;
    const int fc   = lane >> 4;  // k-chunk 0..3

    const int rowbase = blockIdx.x * BM;

    // ---- prologue: stage full A-tile, convert fp32->bf16, ONE barrier ----
    {
        const int srow = tid >> 3;   // 0..63
        const int q    = tid & 7;    // chunk offset within stripe
        const float* xrow = x + (rowbase + srow) * KDIM;
        const int key = (srow & 7) << 3;
#pragma unroll
        for (int i = 0; i < 8; ++i) {
            const int c = i * 8 + q;             // 16B chunk 0..63
            const fv4* src = reinterpret_cast<const fv4*>(xrow + c * 8);
            // bank group = (c ^ (srow&7)) % 8 = (q^..) -> conflict-floor writes
            *reinterpret_cast<iv4*>(&lds_a[srow * 512 + ((c << 3) ^ key)]) =
                pack8(src[0], src[1]);
        }
    }
    __syncthreads();

    // ---- B fragment base: per-lane ptr into repacked W (L2-resident) ----
    const unsigned short* wfrag = wf + (wcol * 64) * 512 + lane * 8;
    const int akey = (fr & 7) << 3;  // row&7 is swizzle-invariant under +m*16

    f32x4 acc[4][4];
#pragma unroll
    for (int m = 0; m < 4; ++m)
#pragma unroll
        for (int n = 0; n < 4; ++n)
            acc[m][n] = (f32x4){0.f, 0.f, 0.f, 0.f};

    // ---- K-loop: 16 steps, fully unrolled, NO barriers ----
#pragma unroll
    for (int kb = 0; kb < NKSTEP; ++kb) {
        bf16x8 bfv[4];
#pragma unroll
        for (int n = 0; n < 4; ++n)
            bfv[n] = *reinterpret_cast<const bf16x8*>(wfrag + (n * 16 + kb) * 512);
        bf16x8 af[4];
#pragma unroll
        for (int m = 0; m < 4; ++m)
            af[m] = *reinterpret_cast<const bf16x8*>(
                &lds_a[(m * 16 + fr) * 512 + ((((kb * 4 + fc) << 3)) ^ akey)]);
#pragma unroll
        for (int n = 0; n < 4; ++n)
#pragma unroll
            for (int m = 0; m < 4; ++m)
                acc[m][n] = __builtin_amdgcn_mfma_f32_16x16x32_bf16(
                    af[m], bfv[n], acc[m][n], 0, 0, 0);
    }

    // ---- epilogue: bias + store (verified round-2/4 layout) ----
    float bv[4];
#pragma unroll
    for (int n = 0; n < 4; ++n)
        bv[n] = bias[wcol * 64 + n * 16 + fr];

    float* obase = out + (rowbase + fc * 4) * NDIM + wcol * 64 + fr;
#pragma unroll
    for (int m = 0; m < 4; ++m)
#pragma unroll
        for (int j = 0; j < 4; ++j) {
            float* orow = obase + (m * 16 + j) * NDIM;
#pragma unroll
            for (int n = 0; n < 4; ++n)
                orow[n * 16] = acc[m][n][j] + bv[n];
        }
}

extern "C" void kernel_launch(void* const* d_in, const int* in_sizes, int n_in,
                              void* d_out, int out_size, void* d_ws, size_t ws_size,
                              hipStream_t stream) {
    const float* x    = (const float*)d_in[0];
    const float* w    = (const float*)d_in[1];
    const float* bias = (const float*)d_in[2];
    float* out        = (float*)d_out;
    unsigned short* wf = (unsigned short*)d_ws;  // 512 KB

    hipLaunchKernelGGL(repack_w_kernel, dim3(128), dim3(256), 0, stream, w, wf);
    hipLaunchKernelGGL(linear_bf16_kernel, dim3(M_TOTAL / BM), dim3(512), 0, stream,
                       x, wf, bias, out);
}